// Round 8
// baseline (244.005 us; speedup 1.0000x reference)
//
#include <hip/hip_runtime.h>
#include <cstdint>

typedef __attribute__((ext_vector_type(8))) short bf16x8;
typedef __attribute__((ext_vector_type(4))) float f32x4;

__device__ __forceinline__ uint32_t bf16_rne(float f) {
    uint32_t u = __float_as_uint(f);
    u += 0x7FFFu + ((u >> 16) & 1u);
    return u >> 16;
}
__device__ __forceinline__ float bf16_f32(uint32_t h) {
    return __uint_as_float(h << 16);
}

__device__ __forceinline__ float tanh_fast(float x) {
    float e = __builtin_amdgcn_exp2f(x * 2.8853900817779268f);
    return fmaf(-2.0f, __builtin_amdgcn_rcpf(e + 1.0f), 1.0f);
}

__device__ __forceinline__ float sel4(float a, float b, float c, float d, int T) {
    float x = (T & 1) ? b : a;
    float y = (T & 1) ? d : c;
    return (T & 2) ? y : x;
}

// ---- prep: W1 (20x64 k-major) -> MFMA A-frag layout, split bf16 hi+lo ----
__global__ __launch_bounds__(256) void prep_kernel(
    const float* __restrict__ W1_0, const float* __restrict__ W1_1,
    const float* __restrict__ W1_2, uint32_t* __restrict__ wf) {
    int m = blockIdx.x;
    const float* W1 = (m == 0) ? W1_0 : (m == 1) ? W1_1 : W1_2;
    int tid = threadIdx.x;
    int Ht = tid >> 6, lane = tid & 63;
    int n = (lane & 15) + 16 * Ht;
    int kb = (lane >> 4) * 8;
    uint32_t dh[4], dl[4];
#pragma unroll
    for (int q = 0; q < 4; ++q) {
        int k0 = kb + 2 * q, k1 = k0 + 1;
        float w0 = (k0 < 20) ? W1[k0 * 64 + n] : 0.0f;
        float w1 = (k1 < 20) ? W1[k1 * 64 + n] : 0.0f;
        uint32_t h0 = bf16_rne(w0), h1 = bf16_rne(w1);
        uint32_t l0 = bf16_rne(w0 - bf16_f32(h0));
        uint32_t l1 = bf16_rne(w1 - bf16_f32(h1));
        dh[q] = h0 | (h1 << 16);
        dl[q] = l0 | (l1 << 16);
    }
    size_t idx = ((size_t)(m * 4 + Ht) * 64 + lane) * 4;
    *(uint4*)(wf + idx)        = make_uint4(dh[0], dh[1], dh[2], dh[3]);
    *(uint4*)(wf + 3072 + idx) = make_uint4(dl[0], dl[1], dl[2], dl[3]);
}

// r8 = r7 (hybrid block-sort via ballots, 4 barriers, no atomics) with the
// butterfly DE-SCRATCHED: the old `float* accs[12]` pointer-array forced the
// 12 accumulators + pointer array onto stack (rule #20) -> ~190 MB/dispatch
// of scratch writeback = the session-long phantom WRITE_SIZE. Named-variable
// unrolled butterfly keeps everything in VGPRs.
__global__ __launch_bounds__(256, 3) void riemann_fused(
    const float* __restrict__ P, const float* __restrict__ U,
    const float* __restrict__ F, const float* __restrict__ cmax,
    const float* __restrict__ cmin,
    const float* __restrict__ b1_ds, const float* __restrict__ W2_ds, const float* __restrict__ b2_ds,
    const float* __restrict__ b1_dr, const float* __restrict__ W2_dr, const float* __restrict__ b2_dr,
    const float* __restrict__ b1_rs, const float* __restrict__ W2_rs, const float* __restrict__ b2_rs,
    const uint32_t* __restrict__ wf,
    float* __restrict__ out, int N) {
    __shared__ __align__(16) uint32_t sm[256 * 36];   // 36 KiB: feats, later flux
    __shared__ int s_cnt[4][4];                       // [wave][label]

    int tid = threadIdx.x;
    int wv = tid >> 6, lane = tid & 63;
    int hi = lane >> 4, lo16 = lane & 15;
    int cell = blockIdx.x * 256 + tid;
    bool valid = cell < N;
    int cg = valid ? cell : N - 1;

    // ---- per-cell prologue (identical to verified baseline) ----
    const float2* P2 = (const float2*)P + (size_t)cg * 3;
    const float2* U2 = (const float2*)U + (size_t)cg * 3;
    const float2* F2 = (const float2*)F + (size_t)cg * 3;
    float2 Pa = P2[0], Pb = P2[1], Pc = P2[2];
    float2 Ua = U2[0], Ub = U2[1], Uc = U2[2];
    float2 Fa = F2[0], Fb = F2[1], Fc = F2[2];
    float cm = cmax[cg];
    float cn = cmin[cg];

    bool flip = Pb.y > Pb.x;
    float fe[20];
    fe[0]  = flip ?  Pa.y :  Pa.x;
    fe[1]  = flip ?  Pa.x :  Pa.y;
    fe[2]  = flip ?  Pb.y :  Pb.x;
    fe[3]  = flip ?  Pb.x :  Pb.y;
    fe[4]  = flip ? -Pc.y :  Pc.x;
    fe[5]  = flip ? -Pc.x :  Pc.y;
    fe[6]  = flip ?  Ua.y :  Ua.x;
    fe[7]  = flip ?  Ua.x :  Ua.y;
    fe[8]  = flip ?  Ub.y :  Ub.x;
    fe[9]  = flip ?  Ub.x :  Ub.y;
    fe[10] = flip ? -Uc.y :  Uc.x;
    fe[11] = flip ? -Uc.x :  Uc.y;
    fe[12] = flip ? -Fa.y :  Fa.x;
    fe[13] = flip ? -Fa.x :  Fa.y;
    fe[14] = flip ? -Fb.y :  Fb.x;
    fe[15] = flip ? -Fb.x :  Fb.y;
    fe[16] = flip ?  Fc.y :  Fc.x;
    fe[17] = flip ?  Fc.x :  Fc.y;
    fe[18] = cm;
    fe[19] = cn;

    // cont: exact f64 compares
    double dd0 = fabs((double)fe[1] - (double)fe[0]);
    double dd1 = fabs((double)fe[3] - (double)fe[2]);
    double dd2 = fabs((double)fe[5] - (double)fe[4]);
    bool cont = fmax(fmax(dd0, dd1), dd2) < 0.005;

    // HLLE
    float inv = __builtin_amdgcn_rcpf(cm - cn);
    float cmn = cm * cn;
    float hl0 = (cm * fe[12] - cn * fe[13] + cmn * (fe[7]  - fe[6]))  * inv;
    float hl1 = (cm * fe[14] - cn * fe[15] + cmn * (fe[9]  - fe[8]))  * inv;
    float hl2 = (cm * fe[16] - cn * fe[17] + cmn * (fe[11] - fe[10])) * inv;

    // classification: f32 fast path + eps-guarded exact f64 fallback
    float c0f = __builtin_amdgcn_sqrtf(1.6666666f * fe[2] * __builtin_amdgcn_rcpf(fe[0]));
    float c1f = __builtin_amdgcn_sqrtf(1.6666666f * fe[3] * __builtin_amdgcn_rcpf(fe[1]));
    float dvf = fe[5] - fe[4];
    float numf = c0f + c1f - (1.0f / 3.0f) * dvf;
    float pz0 = __builtin_amdgcn_exp2f(-0.2f * __builtin_amdgcn_logf(fe[2]));
    float pz1 = __builtin_amdgcn_exp2f(-0.2f * __builtin_amdgcn_logf(fe[3]));
    float denf = c0f * pz0 + c1f * pz1;
    float tq = fmaxf(numf * __builtin_amdgcn_rcpf(denf), 1e-8f);
    float t2 = tq * tq;
    float psf = t2 * t2 * tq;
    float pminf = fminf(fe[2], fe[3]);
    float pmaxf = fmaxf(fe[2], fe[3]);
    float csum3 = 3.0f * (c0f + c1f);
    float vs = dvf - csum3;
    int label = (vs >= 0.0f) ? 3 : (psf < pminf ? 1 : (psf > pmaxf ? 0 : 2));

    const float eps = 2e-4f;
    bool amb = (fabsf(psf - pminf) <= eps * pminf) ||
               (fabsf(psf - pmaxf) <= eps * pmaxf) ||
               (fabsf(vs) <= eps * (fabsf(dvf) + csum3));
    if (__builtin_expect(amb, 0)) {
        double rho0 = (double)fe[0], rho1 = (double)fe[1];
        double p0   = (double)fe[2], p1   = (double)fe[3];
        double v0   = (double)fe[4], v1   = (double)fe[5];
        const double g = 5.0 / 3.0;
        double c0 = sqrt(g * p0 / rho0);
        double c1 = sqrt(g * p1 / rho1);
        double dv = v1 - v0;
        double z = (g - 1.0) / (2.0 * g);
        double num = c0 + c1 - 0.5 * (g - 1.0) * dv;
        double den = c0 / pow(p0, z) + c1 / pow(p1, z);
        double ps = pow(fmax(num / den, 1e-8), 1.0 / z);
        bool vacd = dv >= 2.0 / (g - 1.0) * (c0 + c1);
        label = vacd ? 3 : (ps < fmin(p0, p1) ? 1 : (ps > fmax(p0, p1) ? 0 : 2));
    }
    // work-label: 3 = trivial (cont override or vacuum) -> no MLP needed
    int wl = (!valid || cont || label == 3) ? 3 : label;

    // ---- block-wide bucket sort via ballots + 16-count exchange ----
    uint64_t bal0 = __ballot(wl == 0);
    uint64_t bal1 = __ballot(wl == 1);
    uint64_t bal2 = __ballot(wl == 2);
    int c0n = __popcll(bal0), c1n = __popcll(bal1), c2n = __popcll(bal2);
    uint64_t mym = (wl == 0) ? bal0 : (wl == 1) ? bal1 : (wl == 2) ? bal2
                                                       : ~(bal0 | bal1 | bal2);
    int rank = (int)__popcll(mym & ((1ull << lane) - 1ull));
    if (lane < 4) {
        int c = (lane == 0) ? c0n : (lane == 1) ? c1n : (lane == 2) ? c2n
                                                      : (64 - c0n - c1n - c2n);
        s_cnt[wv][lane] = c;
    }
    __syncthreads();                               // B1: counts visible
    int T0 = s_cnt[0][0] + s_cnt[1][0] + s_cnt[2][0] + s_cnt[3][0];
    int T1 = s_cnt[0][1] + s_cnt[1][1] + s_cnt[2][1] + s_cnt[3][1];
    int T2 = s_cnt[0][2] + s_cnt[1][2] + s_cnt[2][2] + s_cnt[3][2];
    int off1 = T0, off2 = T0 + T1, off3 = T0 + T1 + T2;   // block thresholds
    int basew = (wl == 0) ? 0 : (wl == 1) ? off1 : (wl == 2) ? off2 : off3;
    int prev = 0;
    if (wv > 0) prev += s_cnt[0][wl];
    if (wv > 1) prev += s_cnt[1][wl];
    if (wv > 2) prev += s_cnt[2][wl];
    int slot = basew + prev + rank;                // 0..255, block-wide sorted

    // ---- split bf16 packing ----
    uint32_t pkh[10], pkl[10];
#pragma unroll
    for (int q = 0; q < 10; ++q) {
        float f0 = fe[2 * q], f1 = fe[2 * q + 1];
        uint32_t h0 = bf16_rne(f0), h1 = bf16_rne(f1);
        uint32_t l0 = bf16_rne(f0 - bf16_f32(h0));
        uint32_t l1 = bf16_rne(f1 - bf16_f32(h1));
        pkh[q] = h0 | (h1 << 16);
        pkl[q] = l0 | (l1 << 16);
    }
    // stage at SORTED row (block-wide): hi dwords 0..15, lo 16..31, stride 36
    {
        uint32_t* row = sm + (size_t)slot * 36;
        *(uint4*)(row)      = make_uint4(pkh[0], pkh[1], pkh[2], pkh[3]);
        *(uint4*)(row + 4)  = make_uint4(pkh[4], pkh[5], pkh[6], pkh[7]);
        *(uint4*)(row + 8)  = make_uint4(pkh[8], pkh[9], 0u, 0u);
        *(uint4*)(row + 12) = make_uint4(0u, 0u, 0u, 0u);
        *(uint4*)(row + 16) = make_uint4(pkl[0], pkl[1], pkl[2], pkl[3]);
        *(uint4*)(row + 20) = make_uint4(pkl[4], pkl[5], pkl[6], pkl[7]);
        *(uint4*)(row + 24) = make_uint4(pkl[8], pkl[9], 0u, 0u);
        *(uint4*)(row + 28) = make_uint4(0u, 0u, 0u, 0u);
    }
    __syncthreads();                               // B2: feats staged

    // B-frags: wave's window rows wv*64 + lo16 + 16*Ct (cross-wave data OK)
    int r0w = wv * 64 + lo16;
    const char* sbase = (const char*)sm;
    bf16x8 bfh0 = *(const bf16x8*)(sbase + (size_t)(r0w)      * 144 + hi * 16);
    bf16x8 bfh1 = *(const bf16x8*)(sbase + (size_t)(r0w + 16) * 144 + hi * 16);
    bf16x8 bfh2 = *(const bf16x8*)(sbase + (size_t)(r0w + 32) * 144 + hi * 16);
    bf16x8 bfh3 = *(const bf16x8*)(sbase + (size_t)(r0w + 48) * 144 + hi * 16);
    bf16x8 bfl0 = *(const bf16x8*)(sbase + (size_t)(r0w)      * 144 + 64 + hi * 16);
    bf16x8 bfl1 = *(const bf16x8*)(sbase + (size_t)(r0w + 16) * 144 + 64 + hi * 16);
    bf16x8 bfl2 = *(const bf16x8*)(sbase + (size_t)(r0w + 32) * 144 + 64 + hi * 16);
    bf16x8 bfl3 = *(const bf16x8*)(sbase + (size_t)(r0w + 48) * 144 + 64 + hi * 16);
    __syncthreads();                               // B3: all feat reads done

    // label of sorted positions from block thresholds (register math)
    int lbl0 = (r0w      < off1) ? 0 : (r0w      < off2) ? 1 : (r0w      < off3) ? 2 : 3;
    int lbl1 = (r0w + 16 < off1) ? 0 : (r0w + 16 < off2) ? 1 : (r0w + 16 < off3) ? 2 : 3;
    int lbl2 = (r0w + 32 < off1) ? 0 : (r0w + 32 < off2) ? 1 : (r0w + 32 < off3) ? 2 : 3;
    int lbl3 = (r0w + 48 < off1) ? 0 : (r0w + 48 < off2) ? 1 : (r0w + 48 < off3) ? 2 : 3;

    float oa00 = 0.f, oa01 = 0.f, oa02 = 0.f;
    float oa10 = 0.f, oa11 = 0.f, oa12 = 0.f;
    float oa20 = 0.f, oa21 = 0.f, oa22 = 0.f;
    float oa30 = 0.f, oa31 = 0.f, oa32 = 0.f;

    int wbeg = wv * 64, wend = wbeg + 64;
#pragma unroll 1
    for (int m = 0; m < 3; ++m) {
        int mlo = (m == 0) ? 0 : (m == 1) ? off1 : off2;
        int mhi = (m == 0) ? off1 : (m == 1) ? off2 : off3;
        if (mhi <= wbeg || mlo >= wend) continue;  // wave-uniform model skip
        const float* b1 = (m == 0) ? b1_ds : (m == 1) ? b1_dr : b1_rs;
        const float* W2 = (m == 0) ? W2_ds : (m == 1) ? W2_dr : W2_rs;

        bf16x8 afh[4], afl[4];
        f32x4 b1v[4];
        float w2v[4][12];
#pragma unroll
        for (int Ht = 0; Ht < 4; ++Ht) {
            size_t idx = (size_t)((m * 4 + Ht) * 64 + lane);
            afh[Ht] = __builtin_bit_cast(bf16x8, ((const uint4*)wf)[idx]);
            afl[Ht] = __builtin_bit_cast(bf16x8, ((const uint4*)(wf + 3072))[idx]);
            b1v[Ht] = *(const f32x4*)(b1 + 16 * Ht + 4 * hi);
            const float* w2p = W2 + (16 * Ht + 4 * hi) * 3;
            *(float4*)&w2v[Ht][0] = *(const float4*)(w2p);
            *(float4*)&w2v[Ht][4] = *(const float4*)(w2p + 4);
            *(float4*)&w2v[Ht][8] = *(const float4*)(w2p + 8);
        }
#pragma unroll
        for (int Ct = 0; Ct < 4; ++Ct) {
            int tb = wbeg + 16 * Ct;
            // does label-m interval [mlo,mhi) overlap tile [tb,tb+16)?
            if (mlo < tb + 16 && mhi > tb) {
                int lblC = (Ct == 0) ? lbl0 : (Ct == 1) ? lbl1 : (Ct == 2) ? lbl2 : lbl3;
                bf16x8 bh = (Ct == 0) ? bfh0 : (Ct == 1) ? bfh1 : (Ct == 2) ? bfh2 : bfh3;
                bf16x8 bl = (Ct == 0) ? bfl0 : (Ct == 1) ? bfl1 : (Ct == 2) ? bfl2 : bfl3;
                f32x4 acc[4];
#pragma unroll
                for (int Ht = 0; Ht < 4; ++Ht) acc[Ht] = b1v[Ht];
#pragma unroll
                for (int Ht = 0; Ht < 4; ++Ht)
                    acc[Ht] = __builtin_amdgcn_mfma_f32_16x16x32_bf16(afh[Ht], bh, acc[Ht], 0, 0, 0);
#pragma unroll
                for (int Ht = 0; Ht < 4; ++Ht)
                    acc[Ht] = __builtin_amdgcn_mfma_f32_16x16x32_bf16(afh[Ht], bl, acc[Ht], 0, 0, 0);
#pragma unroll
                for (int Ht = 0; Ht < 4; ++Ht)
                    acc[Ht] = __builtin_amdgcn_mfma_f32_16x16x32_bf16(afl[Ht], bh, acc[Ht], 0, 0, 0);
                float p0 = 0.f, p1 = 0.f, p2 = 0.f;
#pragma unroll
                for (int Ht = 0; Ht < 4; ++Ht) {
#pragma unroll
                    for (int r = 0; r < 4; ++r) {
                        float tv = tanh_fast(acc[Ht][r]);
                        p0 = fmaf(tv, w2v[Ht][r * 3 + 0], p0);
                        p1 = fmaf(tv, w2v[Ht][r * 3 + 1], p1);
                        p2 = fmaf(tv, w2v[Ht][r * 3 + 2], p2);
                    }
                }
                float sel = (lblC == m) ? 1.0f : 0.0f;
                if (Ct == 0) { oa00 = fmaf(sel, p0, oa00); oa01 = fmaf(sel, p1, oa01); oa02 = fmaf(sel, p2, oa02); }
                if (Ct == 1) { oa10 = fmaf(sel, p0, oa10); oa11 = fmaf(sel, p1, oa11); oa12 = fmaf(sel, p2, oa12); }
                if (Ct == 2) { oa20 = fmaf(sel, p0, oa20); oa21 = fmaf(sel, p1, oa21); oa22 = fmaf(sel, p2, oa22); }
                if (Ct == 3) { oa30 = fmaf(sel, p0, oa30); oa31 = fmaf(sel, p1, oa31); oa32 = fmaf(sel, p2, oa32); }
            }
        }
    }

    // ---- butterfly over hi-groups (NAMED variables -> stays in VGPRs) ----
#define BFLY(v) { float t_ = v; t_ += __shfl_xor(t_, 16); t_ += __shfl_xor(t_, 32); v = t_; }
    BFLY(oa00) BFLY(oa01) BFLY(oa02)
    BFLY(oa10) BFLY(oa11) BFLY(oa12)
    BFLY(oa20) BFLY(oa21) BFLY(oa22)
    BFLY(oa30) BFLY(oa31) BFLY(oa32)
#undef BFLY
    float g0 = sel4(oa00, oa10, oa20, oa30, hi);
    float g1 = sel4(oa01, oa11, oa21, oa31, hi);
    float g2 = sel4(oa02, oa12, oa22, oa32, hi);

    // route back: write flux at sorted position, read own slot (cross-wave)
    float (*sm_flux)[3] = (float (*)[3])sm;        // aliases feats (post-B3)
    sm_flux[wbeg + lane][0] = g0;
    sm_flux[wbeg + lane][1] = g1;
    sm_flux[wbeg + lane][2] = g2;
    __syncthreads();                               // B4: flux visible

    float f0, f1, f2;
    if (wl < 3) {
        float bb0 = (wl == 0) ? b2_ds[0] : (wl == 1) ? b2_dr[0] : b2_rs[0];
        float bb1 = (wl == 0) ? b2_ds[1] : (wl == 1) ? b2_dr[1] : b2_rs[1];
        float bb2 = (wl == 0) ? b2_ds[2] : (wl == 1) ? b2_dr[2] : b2_rs[2];
        f0 = sm_flux[slot][0] + bb0;
        f1 = sm_flux[slot][1] + bb1;
        f2 = sm_flux[slot][2] + bb2;
    } else {
        f0 = cont ? hl0 : 0.0f;
        f1 = cont ? hl1 : 0.0f;
        f2 = cont ? hl2 : 0.0f;
    }
    if (flip) { f0 = -f0; f1 = -f1; }

    if (valid) {
        out[(size_t)cell * 3 + 0] = f0;
        out[(size_t)cell * 3 + 1] = f1;
        out[(size_t)cell * 3 + 2] = f2;
    }
}

extern "C" void kernel_launch(void* const* d_in, const int* in_sizes, int n_in,
                              void* d_out, int out_size, void* d_ws, size_t ws_size,
                              hipStream_t stream) {
    const float* P     = (const float*)d_in[0];
    const float* U     = (const float*)d_in[1];
    const float* F     = (const float*)d_in[2];
    const float* cmax  = (const float*)d_in[3];
    const float* cmin  = (const float*)d_in[4];
    const float* W1_ds = (const float*)d_in[5];
    const float* b1_ds = (const float*)d_in[6];
    const float* W2_ds = (const float*)d_in[7];
    const float* b2_ds = (const float*)d_in[8];
    const float* W1_dr = (const float*)d_in[9];
    const float* b1_dr = (const float*)d_in[10];
    const float* W2_dr = (const float*)d_in[11];
    const float* b2_dr = (const float*)d_in[12];
    const float* W1_rs = (const float*)d_in[13];
    const float* b1_rs = (const float*)d_in[14];
    const float* W2_rs = (const float*)d_in[15];
    const float* b2_rs = (const float*)d_in[16];

    int N = in_sizes[3];
    float* out = (float*)d_out;
    uint32_t* wf = (uint32_t*)d_ws;   // 24 KB: hi 12 KB + lo 12 KB

    hipLaunchKernelGGL(prep_kernel, dim3(3), dim3(256), 0, stream,
                       W1_ds, W1_dr, W1_rs, wf);

    dim3 block(256);
    dim3 grid((N + 255) / 256);
    hipLaunchKernelGGL(riemann_fused, grid, block, 0, stream,
                       P, U, F, cmax, cmin,
                       b1_ds, W2_ds, b2_ds,
                       b1_dr, W2_dr, b2_dr,
                       b1_rs, W2_rs, b2_rs,
                       wf, out, N);
}

// Round 10
// 237.573 us; speedup vs baseline: 1.0271x; 1.0271x over previous
//
#include <hip/hip_runtime.h>
#include <cstdint>

typedef __attribute__((ext_vector_type(8))) short bf16x8;
typedef __attribute__((ext_vector_type(4))) float f32x4;

__device__ __forceinline__ uint32_t bf16_rne(float f) {
    uint32_t u = __float_as_uint(f);
    u += 0x7FFFu + ((u >> 16) & 1u);
    return u >> 16;
}
__device__ __forceinline__ float bf16_f32(uint32_t h) {
    return __uint_as_float(h << 16);
}

__device__ __forceinline__ float tanh_fast(float x) {
    float e = __builtin_amdgcn_exp2f(x * 2.8853900817779268f);
    return fmaf(-2.0f, __builtin_amdgcn_rcpf(e + 1.0f), 1.0f);
}

__device__ __forceinline__ float sel4(float a, float b, float c, float d, int T) {
    float x = (T & 1) ? b : a;
    float y = (T & 1) ? d : c;
    return (T & 2) ? y : x;
}
__device__ __forceinline__ int selu4(uint4 v, int T) {
    int x = (T & 1) ? (int)v.y : (int)v.x;
    int y = (T & 1) ? (int)v.w : (int)v.z;
    return (T & 2) ? y : x;
}

// ---- prep: W1 (20x64) -> K-PACKED MFMA A-frags, 2 frags per (m,Ht) ----
// The 3 split-bf16 products (ah*bh k<20, ah*bl k<12.., al*bh k<20) = 60
// slot-pairs packed into TWO K=32 MFMAs:
//   A1 = [ah_0..19 | ah_0..11]      pairs with B1 = [bh_0..19 | bl_0..11]
//   A2 = [ah_12..19 | al_0..19 | 0] pairs with B2 = [bl_12..19 | bh_0..19 | 0]
__global__ __launch_bounds__(256) void prep_kernel(
    const float* __restrict__ W1_0, const float* __restrict__ W1_1,
    const float* __restrict__ W1_2, uint32_t* __restrict__ wf) {
    int m = blockIdx.x;
    const float* W1 = (m == 0) ? W1_0 : (m == 1) ? W1_1 : W1_2;
    int tid = threadIdx.x;
    int Ht = tid >> 6, lane = tid & 63;
    int n = (lane & 15) + 16 * Ht;
    int kb = (lane >> 4) * 8;
    uint32_t d1[4], d2[4];
#pragma unroll
    for (int q = 0; q < 4; ++q) {
        int k0 = kb + 2 * q, k1 = k0 + 1;
        // A1: hi part of W[k] (k<20) or W[k-20] (k>=20)
        int ka = (k0 < 20) ? k0 : k0 - 20;
        int kbb = (k1 < 20) ? k1 : k1 - 20;
        uint32_t h0 = bf16_rne(W1[ka * 64 + n]);
        uint32_t h1 = bf16_rne(W1[kbb * 64 + n]);
        d1[q] = h0 | (h1 << 16);
        // A2: k<8 -> hi(W[k+12]); 8<=k<28 -> lo(W[k-8]); else 0
        uint32_t v0, v1;
        {
            int k = k0;
            if (k < 8) {
                v0 = bf16_rne(W1[(k + 12) * 64 + n]);
            } else if (k < 28) {
                float w = W1[(k - 8) * 64 + n];
                uint32_t h = bf16_rne(w);
                v0 = bf16_rne(w - bf16_f32(h));
            } else v0 = 0u;
        }
        {
            int k = k1;
            if (k < 8) {
                v1 = bf16_rne(W1[(k + 12) * 64 + n]);
            } else if (k < 28) {
                float w = W1[(k - 8) * 64 + n];
                uint32_t h = bf16_rne(w);
                v1 = bf16_rne(w - bf16_f32(h));
            } else v1 = 0u;
        }
        d2[q] = v0 | (v1 << 16);
    }
    size_t idx = ((size_t)(m * 4 + Ht) * 64 + lane) * 4;
    *(uint4*)(wf + idx)        = make_uint4(d1[0], d1[1], d1[2], d1[3]);
    *(uint4*)(wf + 3072 + idx) = make_uint4(d2[0], d2[1], d2[2], d2[3]);
}

// r9: latency-bound fix. LDS cut to EXACTLY 32768 B (5 blocks/CU vs 3-4) via
// K-packed rows of 32 dwords (no pad waste), 2 MFMA per (Ht,Ct) instead of 3.
// Chunk XOR-swizzle (q ^ (row&7)) keeps bank behavior at r7's 8-way parity.
// Counts exchanged through sm itself (one extra barrier; barriers measured
// cheap in r6). WRITE_SIZE counter is a known gfx950 formula artifact; the
// real regime per FETCH (=input size) is latency-bound, not memory-bound.
__global__ __launch_bounds__(256, 3) void riemann_fused(
    const float* __restrict__ P, const float* __restrict__ U,
    const float* __restrict__ F, const float* __restrict__ cmax,
    const float* __restrict__ cmin,
    const float* __restrict__ b1_ds, const float* __restrict__ W2_ds, const float* __restrict__ b2_ds,
    const float* __restrict__ b1_dr, const float* __restrict__ W2_dr, const float* __restrict__ b2_dr,
    const float* __restrict__ b1_rs, const float* __restrict__ W2_rs, const float* __restrict__ b2_rs,
    const uint32_t* __restrict__ wf,
    float* __restrict__ out, int N) {
    __shared__ __align__(16) uint32_t sm[256 * 32];   // exactly 32 KiB

    int tid = threadIdx.x;
    int wv = tid >> 6, lane = tid & 63;
    int hi = lane >> 4, lo16 = lane & 15;
    int cell = blockIdx.x * 256 + tid;
    bool valid = cell < N;
    int cg = valid ? cell : N - 1;

    // ---- per-cell prologue (identical to verified baseline) ----
    const float2* P2 = (const float2*)P + (size_t)cg * 3;
    const float2* U2 = (const float2*)U + (size_t)cg * 3;
    const float2* F2 = (const float2*)F + (size_t)cg * 3;
    float2 Pa = P2[0], Pb = P2[1], Pc = P2[2];
    float2 Ua = U2[0], Ub = U2[1], Uc = U2[2];
    float2 Fa = F2[0], Fb = F2[1], Fc = F2[2];
    float cm = cmax[cg];
    float cn = cmin[cg];

    bool flip = Pb.y > Pb.x;
    float fe[20];
    fe[0]  = flip ?  Pa.y :  Pa.x;
    fe[1]  = flip ?  Pa.x :  Pa.y;
    fe[2]  = flip ?  Pb.y :  Pb.x;
    fe[3]  = flip ?  Pb.x :  Pb.y;
    fe[4]  = flip ? -Pc.y :  Pc.x;
    fe[5]  = flip ? -Pc.x :  Pc.y;
    fe[6]  = flip ?  Ua.y :  Ua.x;
    fe[7]  = flip ?  Ua.x :  Ua.y;
    fe[8]  = flip ?  Ub.y :  Ub.x;
    fe[9]  = flip ?  Ub.x :  Ub.y;
    fe[10] = flip ? -Uc.y :  Uc.x;
    fe[11] = flip ? -Uc.x :  Uc.y;
    fe[12] = flip ? -Fa.y :  Fa.x;
    fe[13] = flip ? -Fa.x :  Fa.y;
    fe[14] = flip ? -Fb.y :  Fb.x;
    fe[15] = flip ? -Fb.x :  Fb.y;
    fe[16] = flip ?  Fc.y :  Fc.x;
    fe[17] = flip ?  Fc.x :  Fc.y;
    fe[18] = cm;
    fe[19] = cn;

    // cont: exact f64 compares
    double dd0 = fabs((double)fe[1] - (double)fe[0]);
    double dd1 = fabs((double)fe[3] - (double)fe[2]);
    double dd2 = fabs((double)fe[5] - (double)fe[4]);
    bool cont = fmax(fmax(dd0, dd1), dd2) < 0.005;

    // HLLE
    float inv = __builtin_amdgcn_rcpf(cm - cn);
    float cmn = cm * cn;
    float hl0 = (cm * fe[12] - cn * fe[13] + cmn * (fe[7]  - fe[6]))  * inv;
    float hl1 = (cm * fe[14] - cn * fe[15] + cmn * (fe[9]  - fe[8]))  * inv;
    float hl2 = (cm * fe[16] - cn * fe[17] + cmn * (fe[11] - fe[10])) * inv;

    // classification: f32 fast path + eps-guarded exact f64 fallback
    float c0f = __builtin_amdgcn_sqrtf(1.6666666f * fe[2] * __builtin_amdgcn_rcpf(fe[0]));
    float c1f = __builtin_amdgcn_sqrtf(1.6666666f * fe[3] * __builtin_amdgcn_rcpf(fe[1]));
    float dvf = fe[5] - fe[4];
    float numf = c0f + c1f - (1.0f / 3.0f) * dvf;
    float pz0 = __builtin_amdgcn_exp2f(-0.2f * __builtin_amdgcn_logf(fe[2]));
    float pz1 = __builtin_amdgcn_exp2f(-0.2f * __builtin_amdgcn_logf(fe[3]));
    float denf = c0f * pz0 + c1f * pz1;
    float tq = fmaxf(numf * __builtin_amdgcn_rcpf(denf), 1e-8f);
    float t2 = tq * tq;
    float psf = t2 * t2 * tq;
    float pminf = fminf(fe[2], fe[3]);
    float pmaxf = fmaxf(fe[2], fe[3]);
    float csum3 = 3.0f * (c0f + c1f);
    float vs = dvf - csum3;
    int label = (vs >= 0.0f) ? 3 : (psf < pminf ? 1 : (psf > pmaxf ? 0 : 2));

    const float eps = 2e-4f;
    bool amb = (fabsf(psf - pminf) <= eps * pminf) ||
               (fabsf(psf - pmaxf) <= eps * pmaxf) ||
               (fabsf(vs) <= eps * (fabsf(dvf) + csum3));
    if (__builtin_expect(amb, 0)) {
        double rho0 = (double)fe[0], rho1 = (double)fe[1];
        double p0   = (double)fe[2], p1   = (double)fe[3];
        double v0   = (double)fe[4], v1   = (double)fe[5];
        const double g = 5.0 / 3.0;
        double c0 = sqrt(g * p0 / rho0);
        double c1 = sqrt(g * p1 / rho1);
        double dv = v1 - v0;
        double z = (g - 1.0) / (2.0 * g);
        double num = c0 + c1 - 0.5 * (g - 1.0) * dv;
        double den = c0 / pow(p0, z) + c1 / pow(p1, z);
        double ps = pow(fmax(num / den, 1e-8), 1.0 / z);
        bool vacd = dv >= 2.0 / (g - 1.0) * (c0 + c1);
        label = vacd ? 3 : (ps < fmin(p0, p1) ? 1 : (ps > fmax(p0, p1) ? 0 : 2));
    }
    // work-label: 3 = trivial (cont override or vacuum) -> no MLP needed
    int wl = (!valid || cont || label == 3) ? 3 : label;

    // ---- block-wide bucket sort via ballots + counts through sm ----
    uint64_t bal0 = __ballot(wl == 0);
    uint64_t bal1 = __ballot(wl == 1);
    uint64_t bal2 = __ballot(wl == 2);
    int c0n = __popcll(bal0), c1n = __popcll(bal1), c2n = __popcll(bal2);
    uint64_t mym = (wl == 0) ? bal0 : (wl == 1) ? bal1 : (wl == 2) ? bal2
                                                       : ~(bal0 | bal1 | bal2);
    int rank = (int)__popcll(mym & ((1ull << lane) - 1ull));
    if (lane < 4) {
        int c = (lane == 0) ? c0n : (lane == 1) ? c1n : (lane == 2) ? c2n
                                                      : (64 - c0n - c1n - c2n);
        sm[wv * 4 + lane] = (uint32_t)c;
    }
    __syncthreads();                               // B1: counts visible
    uint4 ca = *(const uint4*)(sm + 0);            // wave0 [l0..l3]
    uint4 cb = *(const uint4*)(sm + 4);            // wave1
    uint4 cc = *(const uint4*)(sm + 8);            // wave2
    uint4 cd = *(const uint4*)(sm + 12);           // wave3
    __syncthreads();                               // B1b: reads done, sm reusable
    int T0 = (int)(ca.x + cb.x + cc.x + cd.x);
    int T1 = (int)(ca.y + cb.y + cc.y + cd.y);
    int T2 = (int)(ca.z + cb.z + cc.z + cd.z);
    int off1 = T0, off2 = T0 + T1, off3 = T0 + T1 + T2;
    int basew = (wl == 0) ? 0 : (wl == 1) ? off1 : (wl == 2) ? off2 : off3;
    int p0c = selu4(ca, wl), p1c = selu4(cb, wl), p2c = selu4(cc, wl);
    int prev = ((wv > 0) ? p0c : 0) + ((wv > 1) ? p1c : 0) + ((wv > 2) ? p2c : 0);
    int slot = basew + prev + rank;                // 0..255, block-wide sorted

    // ---- split bf16 packing ----
    uint32_t pkh[10], pkl[10];
#pragma unroll
    for (int q = 0; q < 10; ++q) {
        float f0 = fe[2 * q], f1 = fe[2 * q + 1];
        uint32_t h0 = bf16_rne(f0), h1 = bf16_rne(f1);
        uint32_t l0 = bf16_rne(f0 - bf16_f32(h0));
        uint32_t l1 = bf16_rne(f1 - bf16_f32(h1));
        pkh[q] = h0 | (h1 << 16);
        pkl[q] = l0 | (l1 << 16);
    }
    // stage at SORTED row, 32 dwords, chunk-XOR-swizzled:
    // frag1 (logical chunks 0-3): [bh pairs 0..9 | bl pairs 0..5]
    // frag2 (logical chunks 4-7): [bl pairs 6..9 | bh pairs 0..9 | 0 0]
    {
        uint32_t* row = sm + (size_t)slot * 32;
        int sw = slot & 7;
        *(uint4*)(row + 4 * (0 ^ sw)) = make_uint4(pkh[0], pkh[1], pkh[2], pkh[3]);
        *(uint4*)(row + 4 * (1 ^ sw)) = make_uint4(pkh[4], pkh[5], pkh[6], pkh[7]);
        *(uint4*)(row + 4 * (2 ^ sw)) = make_uint4(pkh[8], pkh[9], pkl[0], pkl[1]);
        *(uint4*)(row + 4 * (3 ^ sw)) = make_uint4(pkl[2], pkl[3], pkl[4], pkl[5]);
        *(uint4*)(row + 4 * (4 ^ sw)) = make_uint4(pkl[6], pkl[7], pkl[8], pkl[9]);
        *(uint4*)(row + 4 * (5 ^ sw)) = make_uint4(pkh[0], pkh[1], pkh[2], pkh[3]);
        *(uint4*)(row + 4 * (6 ^ sw)) = make_uint4(pkh[4], pkh[5], pkh[6], pkh[7]);
        *(uint4*)(row + 4 * (7 ^ sw)) = make_uint4(pkh[8], pkh[9], 0u, 0u);
    }
    __syncthreads();                               // B2: feats staged

    // B-frags: wave's window rows wbeg + lo16 + 16*Ct, swizzled chunk reads
    int wbeg = wv * 64, wend = wbeg + 64;
    int rs = lo16 & 7;                             // (row&7) for all 4 tiles
    bf16x8 f1_0, f1_1, f1_2, f1_3, f2_0, f2_1, f2_2, f2_3;
    {
        const uint32_t* r0p = sm + (size_t)(wbeg + lo16) * 32;
        f1_0 = *(const bf16x8*)(r0p +       4 * ((0 + hi) ^ rs));
        f2_0 = *(const bf16x8*)(r0p +       4 * ((4 + hi) ^ rs));
        f1_1 = *(const bf16x8*)(r0p + 512 + 4 * ((0 + hi) ^ rs));
        f2_1 = *(const bf16x8*)(r0p + 512 + 4 * ((4 + hi) ^ rs));
        f1_2 = *(const bf16x8*)(r0p + 1024 + 4 * ((0 + hi) ^ rs));
        f2_2 = *(const bf16x8*)(r0p + 1024 + 4 * ((4 + hi) ^ rs));
        f1_3 = *(const bf16x8*)(r0p + 1536 + 4 * ((0 + hi) ^ rs));
        f2_3 = *(const bf16x8*)(r0p + 1536 + 4 * ((4 + hi) ^ rs));
    }
    __syncthreads();                               // B3: all feat reads done

    // label of sorted positions from block thresholds (register math)
    int r0w = wbeg + lo16;
    int lbl0 = (r0w      < off1) ? 0 : (r0w      < off2) ? 1 : (r0w      < off3) ? 2 : 3;
    int lbl1 = (r0w + 16 < off1) ? 0 : (r0w + 16 < off2) ? 1 : (r0w + 16 < off3) ? 2 : 3;
    int lbl2 = (r0w + 32 < off1) ? 0 : (r0w + 32 < off2) ? 1 : (r0w + 32 < off3) ? 2 : 3;
    int lbl3 = (r0w + 48 < off1) ? 0 : (r0w + 48 < off2) ? 1 : (r0w + 48 < off3) ? 2 : 3;

    float oa00 = 0.f, oa01 = 0.f, oa02 = 0.f;
    float oa10 = 0.f, oa11 = 0.f, oa12 = 0.f;
    float oa20 = 0.f, oa21 = 0.f, oa22 = 0.f;
    float oa30 = 0.f, oa31 = 0.f, oa32 = 0.f;

#pragma unroll 1
    for (int m = 0; m < 3; ++m) {
        int mlo = (m == 0) ? 0 : (m == 1) ? off1 : off2;
        int mhi = (m == 0) ? off1 : (m == 1) ? off2 : off3;
        if (mhi <= wbeg || mlo >= wend) continue;  // wave-uniform model skip
        const float* b1 = (m == 0) ? b1_ds : (m == 1) ? b1_dr : b1_rs;
        const float* W2 = (m == 0) ? W2_ds : (m == 1) ? W2_dr : W2_rs;

        bf16x8 af1[4], af2[4];
        f32x4 b1v[4];
        float w2v[4][12];
#pragma unroll
        for (int Ht = 0; Ht < 4; ++Ht) {
            size_t idx = (size_t)((m * 4 + Ht) * 64 + lane);
            af1[Ht] = __builtin_bit_cast(bf16x8, ((const uint4*)wf)[idx]);
            af2[Ht] = __builtin_bit_cast(bf16x8, ((const uint4*)(wf + 3072))[idx]);
            b1v[Ht] = *(const f32x4*)(b1 + 16 * Ht + 4 * hi);
            const float* w2p = W2 + (16 * Ht + 4 * hi) * 3;
            *(float4*)&w2v[Ht][0] = *(const float4*)(w2p);
            *(float4*)&w2v[Ht][4] = *(const float4*)(w2p + 4);
            *(float4*)&w2v[Ht][8] = *(const float4*)(w2p + 8);
        }
#pragma unroll
        for (int Ct = 0; Ct < 4; ++Ct) {
            int tb = wbeg + 16 * Ct;
            if (mlo < tb + 16 && mhi > tb) {
                int lblC = (Ct == 0) ? lbl0 : (Ct == 1) ? lbl1 : (Ct == 2) ? lbl2 : lbl3;
                bf16x8 bf1 = (Ct == 0) ? f1_0 : (Ct == 1) ? f1_1 : (Ct == 2) ? f1_2 : f1_3;
                bf16x8 bf2 = (Ct == 0) ? f2_0 : (Ct == 1) ? f2_1 : (Ct == 2) ? f2_2 : f2_3;
                f32x4 acc[4];
#pragma unroll
                for (int Ht = 0; Ht < 4; ++Ht) acc[Ht] = b1v[Ht];
#pragma unroll
                for (int Ht = 0; Ht < 4; ++Ht)
                    acc[Ht] = __builtin_amdgcn_mfma_f32_16x16x32_bf16(af1[Ht], bf1, acc[Ht], 0, 0, 0);
#pragma unroll
                for (int Ht = 0; Ht < 4; ++Ht)
                    acc[Ht] = __builtin_amdgcn_mfma_f32_16x16x32_bf16(af2[Ht], bf2, acc[Ht], 0, 0, 0);
                float p0 = 0.f, p1 = 0.f, p2 = 0.f;
#pragma unroll
                for (int Ht = 0; Ht < 4; ++Ht) {
#pragma unroll
                    for (int r = 0; r < 4; ++r) {
                        float tv = tanh_fast(acc[Ht][r]);
                        p0 = fmaf(tv, w2v[Ht][r * 3 + 0], p0);
                        p1 = fmaf(tv, w2v[Ht][r * 3 + 1], p1);
                        p2 = fmaf(tv, w2v[Ht][r * 3 + 2], p2);
                    }
                }
                float sel = (lblC == m) ? 1.0f : 0.0f;
                if (Ct == 0) { oa00 = fmaf(sel, p0, oa00); oa01 = fmaf(sel, p1, oa01); oa02 = fmaf(sel, p2, oa02); }
                if (Ct == 1) { oa10 = fmaf(sel, p0, oa10); oa11 = fmaf(sel, p1, oa11); oa12 = fmaf(sel, p2, oa12); }
                if (Ct == 2) { oa20 = fmaf(sel, p0, oa20); oa21 = fmaf(sel, p1, oa21); oa22 = fmaf(sel, p2, oa22); }
                if (Ct == 3) { oa30 = fmaf(sel, p0, oa30); oa31 = fmaf(sel, p1, oa31); oa32 = fmaf(sel, p2, oa32); }
            }
        }
    }

    // ---- butterfly over hi-groups (r7-measured form) ----
    {
        float* accs[12] = {&oa00, &oa01, &oa02, &oa10, &oa11, &oa12,
                           &oa20, &oa21, &oa22, &oa30, &oa31, &oa32};
#pragma unroll
        for (int q = 0; q < 12; ++q) {
            float v = *accs[q];
            v += __shfl_xor(v, 16);
            v += __shfl_xor(v, 32);
            *accs[q] = v;
        }
    }
    float g0 = sel4(oa00, oa10, oa20, oa30, hi);
    float g1 = sel4(oa01, oa11, oa21, oa31, hi);
    float g2 = sel4(oa02, oa12, oa22, oa32, hi);

    // route back: write flux at sorted position, read own slot (cross-wave)
    float (*sm_flux)[3] = (float (*)[3])sm;        // aliases feats (post-B3)
    sm_flux[wbeg + lane][0] = g0;
    sm_flux[wbeg + lane][1] = g1;
    sm_flux[wbeg + lane][2] = g2;
    __syncthreads();                               // B4: flux visible

    float f0, f1, f2;
    if (wl < 3) {
        float bb0 = (wl == 0) ? b2_ds[0] : (wl == 1) ? b2_dr[0] : b2_rs[0];
        float bb1 = (wl == 0) ? b2_ds[1] : (wl == 1) ? b2_dr[1] : b2_rs[1];
        float bb2 = (wl == 0) ? b2_ds[2] : (wl == 1) ? b2_dr[2] : b2_rs[2];
        f0 = sm_flux[slot][0] + bb0;
        f1 = sm_flux[slot][1] + bb1;
        f2 = sm_flux[slot][2] + bb2;
    } else {
        f0 = cont ? hl0 : 0.0f;
        f1 = cont ? hl1 : 0.0f;
        f2 = cont ? hl2 : 0.0f;
    }
    if (flip) { f0 = -f0; f1 = -f1; }

    if (valid) {
        out[(size_t)cell * 3 + 0] = f0;
        out[(size_t)cell * 3 + 1] = f1;
        out[(size_t)cell * 3 + 2] = f2;
    }
}

extern "C" void kernel_launch(void* const* d_in, const int* in_sizes, int n_in,
                              void* d_out, int out_size, void* d_ws, size_t ws_size,
                              hipStream_t stream) {
    const float* P     = (const float*)d_in[0];
    const float* U     = (const float*)d_in[1];
    const float* F     = (const float*)d_in[2];
    const float* cmax  = (const float*)d_in[3];
    const float* cmin  = (const float*)d_in[4];
    const float* W1_ds = (const float*)d_in[5];
    const float* b1_ds = (const float*)d_in[6];
    const float* W2_ds = (const float*)d_in[7];
    const float* b2_ds = (const float*)d_in[8];
    const float* W1_dr = (const float*)d_in[9];
    const float* b1_dr = (const float*)d_in[10];
    const float* W2_dr = (const float*)d_in[11];
    const float* b2_dr = (const float*)d_in[12];
    const float* W1_rs = (const float*)d_in[13];
    const float* b1_rs = (const float*)d_in[14];
    const float* W2_rs = (const float*)d_in[15];
    const float* b2_rs = (const float*)d_in[16];

    int N = in_sizes[3];
    float* out = (float*)d_out;
    uint32_t* wf = (uint32_t*)d_ws;   // 24 KB: A1 frags 12 KB + A2 frags 12 KB

    hipLaunchKernelGGL(prep_kernel, dim3(3), dim3(256), 0, stream,
                       W1_ds, W1_dr, W1_rs, wf);

    dim3 block(256);
    dim3 grid((N + 255) / 256);
    hipLaunchKernelGGL(riemann_fused, grid, block, 0, stream,
                       P, U, F, cmax, cmin,
                       b1_ds, W2_ds, b2_ds,
                       b1_dr, W2_dr, b2_dr,
                       b1_rs, W2_rs, b2_rs,
                       wf, out, N);
}

// Round 11
// 187.487 us; speedup vs baseline: 1.3014x; 1.2671x over previous
//
#include <hip/hip_runtime.h>
#include <cstdint>

typedef __attribute__((ext_vector_type(8))) short bf16x8;
typedef __attribute__((ext_vector_type(4))) float f32x4;

__device__ __forceinline__ uint32_t bf16_rne(float f) {
    uint32_t u = __float_as_uint(f);
    u += 0x7FFFu + ((u >> 16) & 1u);
    return u >> 16;
}
__device__ __forceinline__ float bf16_f32(uint32_t h) {
    return __uint_as_float(h << 16);
}

__device__ __forceinline__ float tanh_fast(float x) {
    float e = __builtin_amdgcn_exp2f(x * 2.8853900817779268f);
    return fmaf(-2.0f, __builtin_amdgcn_rcpf(e + 1.0f), 1.0f);
}

__device__ __forceinline__ int selu4(uint4 v, int T) {
    int x = (T & 1) ? (int)v.y : (int)v.x;
    int y = (T & 1) ? (int)v.w : (int)v.z;
    return (T & 2) ? y : x;
}

// ---- prep: W1 (20x64) -> K-PACKED MFMA A-frags (r10-verified) ----
__global__ __launch_bounds__(256) void prep_kernel(
    const float* __restrict__ W1_0, const float* __restrict__ W1_1,
    const float* __restrict__ W1_2, uint32_t* __restrict__ wf) {
    int m = blockIdx.x;
    const float* W1 = (m == 0) ? W1_0 : (m == 1) ? W1_1 : W1_2;
    int tid = threadIdx.x;
    int Ht = tid >> 6, lane = tid & 63;
    int n = (lane & 15) + 16 * Ht;
    int kb = (lane >> 4) * 8;
    uint32_t d1[4], d2[4];
#pragma unroll
    for (int q = 0; q < 4; ++q) {
        int k0 = kb + 2 * q, k1 = k0 + 1;
        int ka = (k0 < 20) ? k0 : k0 - 20;
        int kbb = (k1 < 20) ? k1 : k1 - 20;
        uint32_t h0 = bf16_rne(W1[ka * 64 + n]);
        uint32_t h1 = bf16_rne(W1[kbb * 64 + n]);
        d1[q] = h0 | (h1 << 16);
        uint32_t v0, v1;
        {
            int k = k0;
            if (k < 8) {
                v0 = bf16_rne(W1[(k + 12) * 64 + n]);
            } else if (k < 28) {
                float w = W1[(k - 8) * 64 + n];
                uint32_t h = bf16_rne(w);
                v0 = bf16_rne(w - bf16_f32(h));
            } else v0 = 0u;
        }
        {
            int k = k1;
            if (k < 8) {
                v1 = bf16_rne(W1[(k + 12) * 64 + n]);
            } else if (k < 28) {
                float w = W1[(k - 8) * 64 + n];
                uint32_t h = bf16_rne(w);
                v1 = bf16_rne(w - bf16_f32(h));
            } else v1 = 0u;
        }
        d2[q] = v0 | (v1 << 16);
    }
    size_t idx = ((size_t)(m * 4 + Ht) * 64 + lane) * 4;
    *(uint4*)(wf + idx)        = make_uint4(d1[0], d1[1], d1[2], d1[3]);
    *(uint4*)(wf + 3072 + idx) = make_uint4(d2[0], d2[1], d2[2], d2[3]);
}

// Per-cell prologue+classify+pack; numerics identical to verified r10 path.
struct Cell {
    uint32_t pkh[10], pkl[10];
    float hl0, hl1, hl2;
    int wl;
    bool cont, flip;
};

__device__ __forceinline__ void do_cell(
    const float* __restrict__ P, const float* __restrict__ U,
    const float* __restrict__ F, const float* __restrict__ cmax,
    const float* __restrict__ cmin, int cg, bool valid, Cell& o) {
    const float2* P2 = (const float2*)P + (size_t)cg * 3;
    const float2* U2 = (const float2*)U + (size_t)cg * 3;
    const float2* F2 = (const float2*)F + (size_t)cg * 3;
    float2 Pa = P2[0], Pb = P2[1], Pc = P2[2];
    float2 Ua = U2[0], Ub = U2[1], Uc = U2[2];
    float2 Fa = F2[0], Fb = F2[1], Fc = F2[2];
    float cm = cmax[cg];
    float cn = cmin[cg];

    bool flip = Pb.y > Pb.x;
    float fe[20];
    fe[0]  = flip ?  Pa.y :  Pa.x;
    fe[1]  = flip ?  Pa.x :  Pa.y;
    fe[2]  = flip ?  Pb.y :  Pb.x;
    fe[3]  = flip ?  Pb.x :  Pb.y;
    fe[4]  = flip ? -Pc.y :  Pc.x;
    fe[5]  = flip ? -Pc.x :  Pc.y;
    fe[6]  = flip ?  Ua.y :  Ua.x;
    fe[7]  = flip ?  Ua.x :  Ua.y;
    fe[8]  = flip ?  Ub.y :  Ub.x;
    fe[9]  = flip ?  Ub.x :  Ub.y;
    fe[10] = flip ? -Uc.y :  Uc.x;
    fe[11] = flip ? -Uc.x :  Uc.y;
    fe[12] = flip ? -Fa.y :  Fa.x;
    fe[13] = flip ? -Fa.x :  Fa.y;
    fe[14] = flip ? -Fb.y :  Fb.x;
    fe[15] = flip ? -Fb.x :  Fb.y;
    fe[16] = flip ?  Fc.y :  Fc.x;
    fe[17] = flip ?  Fc.x :  Fc.y;
    fe[18] = cm;
    fe[19] = cn;

    double dd0 = fabs((double)fe[1] - (double)fe[0]);
    double dd1 = fabs((double)fe[3] - (double)fe[2]);
    double dd2 = fabs((double)fe[5] - (double)fe[4]);
    bool cont = fmax(fmax(dd0, dd1), dd2) < 0.005;

    float inv = __builtin_amdgcn_rcpf(cm - cn);
    float cmn = cm * cn;
    o.hl0 = (cm * fe[12] - cn * fe[13] + cmn * (fe[7]  - fe[6]))  * inv;
    o.hl1 = (cm * fe[14] - cn * fe[15] + cmn * (fe[9]  - fe[8]))  * inv;
    o.hl2 = (cm * fe[16] - cn * fe[17] + cmn * (fe[11] - fe[10])) * inv;

    float c0f = __builtin_amdgcn_sqrtf(1.6666666f * fe[2] * __builtin_amdgcn_rcpf(fe[0]));
    float c1f = __builtin_amdgcn_sqrtf(1.6666666f * fe[3] * __builtin_amdgcn_rcpf(fe[1]));
    float dvf = fe[5] - fe[4];
    float numf = c0f + c1f - (1.0f / 3.0f) * dvf;
    float pz0 = __builtin_amdgcn_exp2f(-0.2f * __builtin_amdgcn_logf(fe[2]));
    float pz1 = __builtin_amdgcn_exp2f(-0.2f * __builtin_amdgcn_logf(fe[3]));
    float denf = c0f * pz0 + c1f * pz1;
    float tq = fmaxf(numf * __builtin_amdgcn_rcpf(denf), 1e-8f);
    float t2 = tq * tq;
    float psf = t2 * t2 * tq;
    float pminf = fminf(fe[2], fe[3]);
    float pmaxf = fmaxf(fe[2], fe[3]);
    float csum3 = 3.0f * (c0f + c1f);
    float vs = dvf - csum3;
    int label = (vs >= 0.0f) ? 3 : (psf < pminf ? 1 : (psf > pmaxf ? 0 : 2));

    const float eps = 2e-4f;
    bool amb = (fabsf(psf - pminf) <= eps * pminf) ||
               (fabsf(psf - pmaxf) <= eps * pmaxf) ||
               (fabsf(vs) <= eps * (fabsf(dvf) + csum3));
    if (__builtin_expect(amb, 0)) {
        double rho0 = (double)fe[0], rho1 = (double)fe[1];
        double p0   = (double)fe[2], p1   = (double)fe[3];
        double v0   = (double)fe[4], v1   = (double)fe[5];
        const double g = 5.0 / 3.0;
        double c0 = sqrt(g * p0 / rho0);
        double c1 = sqrt(g * p1 / rho1);
        double dv = v1 - v0;
        double z = (g - 1.0) / (2.0 * g);
        double num = c0 + c1 - 0.5 * (g - 1.0) * dv;
        double den = c0 / pow(p0, z) + c1 / pow(p1, z);
        double ps = pow(fmax(num / den, 1e-8), 1.0 / z);
        bool vacd = dv >= 2.0 / (g - 1.0) * (c0 + c1);
        label = vacd ? 3 : (ps < fmin(p0, p1) ? 1 : (ps > fmax(p0, p1) ? 0 : 2));
    }
    o.cont = cont;
    o.flip = flip;
    o.wl = (!valid || cont || label == 3) ? 3 : label;

#pragma unroll
    for (int q = 0; q < 10; ++q) {
        float f0 = fe[2 * q], f1 = fe[2 * q + 1];
        uint32_t h0 = bf16_rne(f0), h1 = bf16_rne(f1);
        uint32_t l0 = bf16_rne(f0 - bf16_f32(h0));
        uint32_t l1 = bf16_rne(f1 - bf16_f32(h1));
        o.pkh[q] = h0 | (h1 << 16);
        o.pkl[q] = l0 | (l1 << 16);
    }
}

// r11: 2 cells/thread, 512-cell block-sort. VGPR cap was the session-long
// occupancy binder (84 -> 3 waves/SIMD; r2: (256,4) forces 64 -> spill).
// (256,2)=128-cap with 2 chains/thread gives 4 independent cell-chains per
// SIMD, halves per-cell sort/barrier/weight-load overhead. Register diet:
// W2/b1 staged in LDS, B-frags lazy-loaded per tile, per-pass butterfly
// accumulates straight into a wave-private LDS flux buffer (no oa array).
__global__ __launch_bounds__(256, 2) void riemann_fused(
    const float* __restrict__ P, const float* __restrict__ U,
    const float* __restrict__ F, const float* __restrict__ cmax,
    const float* __restrict__ cmin,
    const float* __restrict__ b1_ds, const float* __restrict__ W2_ds, const float* __restrict__ b2_ds,
    const float* __restrict__ b1_dr, const float* __restrict__ W2_dr, const float* __restrict__ b2_dr,
    const float* __restrict__ b1_rs, const float* __restrict__ W2_rs, const float* __restrict__ b2_rs,
    const uint32_t* __restrict__ wf,
    float* __restrict__ out, int N) {
    __shared__ __align__(16) uint32_t sm[512 * 32];      // 64 KiB feats
    __shared__ __align__(16) float sw2[3][64][4];        // 3 KiB W2 (padded)
    __shared__ __align__(16) float sb1[3][64];           // 768 B b1
    __shared__ __align__(16) float sflux[512][3];        // 6 KiB flux
    __shared__ __align__(16) uint32_t scnt[32];          // 8 groups x 4 labels

    int tid = threadIdx.x;
    int wv = tid >> 6, lane = tid & 63;
    int hi = lane >> 4, lo16 = lane & 15;
    int base = blockIdx.x * 512;
    int cA = base + tid, cB = base + 256 + tid;
    bool vA = cA < N, vB = cB < N;

    // stage weights early (global loads overlap the prologue)
    if (tid < 192) {
        int mm = tid >> 6, j = tid & 63;
        const float* W2m = (mm == 0) ? W2_ds : (mm == 1) ? W2_dr : W2_rs;
        const float* b1m = (mm == 0) ? b1_ds : (mm == 1) ? b1_dr : b1_rs;
        sw2[mm][j][0] = W2m[j * 3 + 0];
        sw2[mm][j][1] = W2m[j * 3 + 1];
        sw2[mm][j][2] = W2m[j * 3 + 2];
        sw2[mm][j][3] = 0.f;
        sb1[mm][j] = b1m[j];
    }

    Cell oA, oB;
    do_cell(P, U, F, cmax, cmin, vA ? cA : N - 1, vA, oA);
    do_cell(P, U, F, cmax, cmin, vB ? cB : N - 1, vB, oB);

    // ---- block-wide (512) bucket sort via 8 ballot groups ----
    uint64_t aA0 = __ballot(oA.wl == 0);
    uint64_t aA1 = __ballot(oA.wl == 1);
    uint64_t aA2 = __ballot(oA.wl == 2);
    uint64_t aB0 = __ballot(oB.wl == 0);
    uint64_t aB1 = __ballot(oB.wl == 1);
    uint64_t aB2 = __ballot(oB.wl == 2);
    int cA0 = __popcll(aA0), cA1 = __popcll(aA1), cA2 = __popcll(aA2);
    int cB0 = __popcll(aB0), cB1 = __popcll(aB1), cB2 = __popcll(aB2);
    uint64_t lmask = (1ull << lane) - 1ull;
    uint64_t mA = (oA.wl == 0) ? aA0 : (oA.wl == 1) ? aA1 : (oA.wl == 2) ? aA2
                                                         : ~(aA0 | aA1 | aA2);
    uint64_t mB = (oB.wl == 0) ? aB0 : (oB.wl == 1) ? aB1 : (oB.wl == 2) ? aB2
                                                         : ~(aB0 | aB1 | aB2);
    int rankA = (int)__popcll(mA & lmask);
    int rankB = (int)__popcll(mB & lmask);
    if (lane < 8) {
        int l = lane & 3;
        int g = (lane < 4) ? wv : 4 + wv;
        int c = (lane < 4)
            ? ((l == 0) ? cA0 : (l == 1) ? cA1 : (l == 2) ? cA2 : (64 - cA0 - cA1 - cA2))
            : ((l == 0) ? cB0 : (l == 1) ? cB1 : (l == 2) ? cB2 : (64 - cB0 - cB1 - cB2));
        scnt[g * 4 + l] = (uint32_t)c;
    }
    __syncthreads();                               // B1: counts + weights visible
    int T0 = 0, T1 = 0, T2 = 0, prevA = 0, prevB = 0;
#pragma unroll
    for (int g = 0; g < 8; ++g) {
        uint4 q = *(const uint4*)(scnt + 4 * g);
        T0 += (int)q.x; T1 += (int)q.y; T2 += (int)q.z;
        int cag = selu4(q, oA.wl);
        int cbg = selu4(q, oB.wl);
        if (g < wv) prevA += cag;
        if (g < 4 + wv) prevB += cbg;
    }
    int off1 = T0, off2 = T0 + T1, off3 = T0 + T1 + T2;
    int baseA = (oA.wl == 0) ? 0 : (oA.wl == 1) ? off1 : (oA.wl == 2) ? off2 : off3;
    int baseB = (oB.wl == 0) ? 0 : (oB.wl == 1) ? off1 : (oB.wl == 2) ? off2 : off3;
    int slotA = baseA + prevA + rankA;             // 0..511
    int slotB = baseB + prevB + rankB;

    // ---- stage both cells at sorted rows (r10 layout + chunk swizzle) ----
    {
        uint32_t* row = sm + (size_t)slotA * 32;
        int sw = slotA & 7;
        *(uint4*)(row + 4 * (0 ^ sw)) = make_uint4(oA.pkh[0], oA.pkh[1], oA.pkh[2], oA.pkh[3]);
        *(uint4*)(row + 4 * (1 ^ sw)) = make_uint4(oA.pkh[4], oA.pkh[5], oA.pkh[6], oA.pkh[7]);
        *(uint4*)(row + 4 * (2 ^ sw)) = make_uint4(oA.pkh[8], oA.pkh[9], oA.pkl[0], oA.pkl[1]);
        *(uint4*)(row + 4 * (3 ^ sw)) = make_uint4(oA.pkl[2], oA.pkl[3], oA.pkl[4], oA.pkl[5]);
        *(uint4*)(row + 4 * (4 ^ sw)) = make_uint4(oA.pkl[6], oA.pkl[7], oA.pkl[8], oA.pkl[9]);
        *(uint4*)(row + 4 * (5 ^ sw)) = make_uint4(oA.pkh[0], oA.pkh[1], oA.pkh[2], oA.pkh[3]);
        *(uint4*)(row + 4 * (6 ^ sw)) = make_uint4(oA.pkh[4], oA.pkh[5], oA.pkh[6], oA.pkh[7]);
        *(uint4*)(row + 4 * (7 ^ sw)) = make_uint4(oA.pkh[8], oA.pkh[9], 0u, 0u);
    }
    {
        uint32_t* row = sm + (size_t)slotB * 32;
        int sw = slotB & 7;
        *(uint4*)(row + 4 * (0 ^ sw)) = make_uint4(oB.pkh[0], oB.pkh[1], oB.pkh[2], oB.pkh[3]);
        *(uint4*)(row + 4 * (1 ^ sw)) = make_uint4(oB.pkh[4], oB.pkh[5], oB.pkh[6], oB.pkh[7]);
        *(uint4*)(row + 4 * (2 ^ sw)) = make_uint4(oB.pkh[8], oB.pkh[9], oB.pkl[0], oB.pkl[1]);
        *(uint4*)(row + 4 * (3 ^ sw)) = make_uint4(oB.pkl[2], oB.pkl[3], oB.pkl[4], oB.pkl[5]);
        *(uint4*)(row + 4 * (4 ^ sw)) = make_uint4(oB.pkl[6], oB.pkl[7], oB.pkl[8], oB.pkl[9]);
        *(uint4*)(row + 4 * (5 ^ sw)) = make_uint4(oB.pkh[0], oB.pkh[1], oB.pkh[2], oB.pkh[3]);
        *(uint4*)(row + 4 * (6 ^ sw)) = make_uint4(oB.pkh[4], oB.pkh[5], oB.pkh[6], oB.pkh[7]);
        *(uint4*)(row + 4 * (7 ^ sw)) = make_uint4(oB.pkh[8], oB.pkh[9], 0u, 0u);
    }
    // zero own wave's flux window (rows 2*tid, 2*tid+1 == [wv*128, wv*128+128))
    sflux[2 * tid][0] = 0.f; sflux[2 * tid][1] = 0.f; sflux[2 * tid][2] = 0.f;
    sflux[2 * tid + 1][0] = 0.f; sflux[2 * tid + 1][1] = 0.f; sflux[2 * tid + 1][2] = 0.f;
    __syncthreads();                               // B2: feats staged

    // ---- MFMA phase: wave owns 128 sorted rows = 8 tiles ----
    int wbeg = wv * 128, wend = wbeg + 128;
    int rs = lo16 & 7;
#pragma unroll 1
    for (int m = 0; m < 3; ++m) {
        int mlo = (m == 0) ? 0 : (m == 1) ? off1 : off2;
        int mhi = (m == 0) ? off1 : (m == 1) ? off2 : off3;
        if (mhi <= wbeg || mlo >= wend) continue;
        bf16x8 af1[4], af2[4];
#pragma unroll
        for (int Ht = 0; Ht < 4; ++Ht) {
            size_t idx = (size_t)((m * 4 + Ht) * 64 + lane);
            af1[Ht] = __builtin_bit_cast(bf16x8, ((const uint4*)wf)[idx]);
            af2[Ht] = __builtin_bit_cast(bf16x8, ((const uint4*)(wf + 3072))[idx]);
        }
#pragma unroll
        for (int t = 0; t < 8; ++t) {
            int tb = wbeg + 16 * t;
            if (mlo < tb + 16 && mhi > tb) {
                const uint32_t* rp = sm + (size_t)(tb + lo16) * 32;
                bf16x8 bf1 = *(const bf16x8*)(rp + 4 * ((0 + hi) ^ rs));
                bf16x8 bf2 = *(const bf16x8*)(rp + 4 * ((4 + hi) ^ rs));
                f32x4 acc[4];
#pragma unroll
                for (int Ht = 0; Ht < 4; ++Ht)
                    acc[Ht] = *(const f32x4*)&sb1[m][16 * Ht + 4 * hi];
#pragma unroll
                for (int Ht = 0; Ht < 4; ++Ht)
                    acc[Ht] = __builtin_amdgcn_mfma_f32_16x16x32_bf16(af1[Ht], bf1, acc[Ht], 0, 0, 0);
#pragma unroll
                for (int Ht = 0; Ht < 4; ++Ht)
                    acc[Ht] = __builtin_amdgcn_mfma_f32_16x16x32_bf16(af2[Ht], bf2, acc[Ht], 0, 0, 0);
                float p0 = 0.f, p1 = 0.f, p2 = 0.f;
#pragma unroll
                for (int Ht = 0; Ht < 4; ++Ht) {
#pragma unroll
                    for (int r = 0; r < 4; ++r) {
                        float tv = tanh_fast(acc[Ht][r]);
                        f32x4 w = *(const f32x4*)&sw2[m][16 * Ht + 4 * hi + r][0];
                        p0 = fmaf(tv, w[0], p0);
                        p1 = fmaf(tv, w[1], p1);
                        p2 = fmaf(tv, w[2], p2);
                    }
                }
                int rowp = tb + lo16;
                int lblC = (rowp < off1) ? 0 : (rowp < off2) ? 1 : (rowp < off3) ? 2 : 3;
                float sel = (lblC == m) ? 1.0f : 0.0f;
                p0 *= sel; p1 *= sel; p2 *= sel;
                p0 += __shfl_xor(p0, 16); p0 += __shfl_xor(p0, 32);
                p1 += __shfl_xor(p1, 16); p1 += __shfl_xor(p1, 32);
                p2 += __shfl_xor(p2, 16); p2 += __shfl_xor(p2, 32);
                if (hi == 0) {                     // 16 lanes write 16 rows
                    sflux[rowp][0] += p0;
                    sflux[rowp][1] += p1;
                    sflux[rowp][2] += p2;
                }
            }
        }
    }
    __syncthreads();                               // B3: flux visible

    // ---- epilogue for both cells ----
    {
        float f0, f1, f2;
        if (oA.wl < 3) {
            float bb0 = (oA.wl == 0) ? b2_ds[0] : (oA.wl == 1) ? b2_dr[0] : b2_rs[0];
            float bb1 = (oA.wl == 0) ? b2_ds[1] : (oA.wl == 1) ? b2_dr[1] : b2_rs[1];
            float bb2 = (oA.wl == 0) ? b2_ds[2] : (oA.wl == 1) ? b2_dr[2] : b2_rs[2];
            f0 = sflux[slotA][0] + bb0;
            f1 = sflux[slotA][1] + bb1;
            f2 = sflux[slotA][2] + bb2;
        } else {
            f0 = oA.cont ? oA.hl0 : 0.0f;
            f1 = oA.cont ? oA.hl1 : 0.0f;
            f2 = oA.cont ? oA.hl2 : 0.0f;
        }
        if (oA.flip) { f0 = -f0; f1 = -f1; }
        if (vA) {
            out[(size_t)cA * 3 + 0] = f0;
            out[(size_t)cA * 3 + 1] = f1;
            out[(size_t)cA * 3 + 2] = f2;
        }
    }
    {
        float f0, f1, f2;
        if (oB.wl < 3) {
            float bb0 = (oB.wl == 0) ? b2_ds[0] : (oB.wl == 1) ? b2_dr[0] : b2_rs[0];
            float bb1 = (oB.wl == 0) ? b2_ds[1] : (oB.wl == 1) ? b2_dr[1] : b2_rs[1];
            float bb2 = (oB.wl == 0) ? b2_ds[2] : (oB.wl == 1) ? b2_dr[2] : b2_rs[2];
            f0 = sflux[slotB][0] + bb0;
            f1 = sflux[slotB][1] + bb1;
            f2 = sflux[slotB][2] + bb2;
        } else {
            f0 = oB.cont ? oB.hl0 : 0.0f;
            f1 = oB.cont ? oB.hl1 : 0.0f;
            f2 = oB.cont ? oB.hl2 : 0.0f;
        }
        if (oB.flip) { f0 = -f0; f1 = -f1; }
        if (vB) {
            out[(size_t)cB * 3 + 0] = f0;
            out[(size_t)cB * 3 + 1] = f1;
            out[(size_t)cB * 3 + 2] = f2;
        }
    }
}

extern "C" void kernel_launch(void* const* d_in, const int* in_sizes, int n_in,
                              void* d_out, int out_size, void* d_ws, size_t ws_size,
                              hipStream_t stream) {
    const float* P     = (const float*)d_in[0];
    const float* U     = (const float*)d_in[1];
    const float* F     = (const float*)d_in[2];
    const float* cmax  = (const float*)d_in[3];
    const float* cmin  = (const float*)d_in[4];
    const float* W1_ds = (const float*)d_in[5];
    const float* b1_ds = (const float*)d_in[6];
    const float* W2_ds = (const float*)d_in[7];
    const float* b2_ds = (const float*)d_in[8];
    const float* W1_dr = (const float*)d_in[9];
    const float* b1_dr = (const float*)d_in[10];
    const float* W2_dr = (const float*)d_in[11];
    const float* b2_dr = (const float*)d_in[12];
    const float* W1_rs = (const float*)d_in[13];
    const float* b1_rs = (const float*)d_in[14];
    const float* W2_rs = (const float*)d_in[15];
    const float* b2_rs = (const float*)d_in[16];

    int N = in_sizes[3];
    float* out = (float*)d_out;
    uint32_t* wf = (uint32_t*)d_ws;   // 24 KB: A1 frags 12 KB + A2 frags 12 KB

    hipLaunchKernelGGL(prep_kernel, dim3(3), dim3(256), 0, stream,
                       W1_ds, W1_dr, W1_rs, wf);

    dim3 block(256);
    dim3 grid((N + 511) / 512);
    hipLaunchKernelGGL(riemann_fused, grid, block, 0, stream,
                       P, U, F, cmax, cmin,
                       b1_ds, W2_ds, b2_ds,
                       b1_dr, W2_dr, b2_dr,
                       b1_rs, W2_rs, b2_rs,
                       wf, out, N);
}

// Round 13
// 172.854 us; speedup vs baseline: 1.4116x; 1.0847x over previous
//
#include <hip/hip_runtime.h>
#include <cstdint>

typedef __attribute__((ext_vector_type(8))) short bf16x8;
typedef __attribute__((ext_vector_type(4))) float f32x4;

__device__ __forceinline__ uint32_t bf16_rne(float f) {
    uint32_t u = __float_as_uint(f);
    u += 0x7FFFu + ((u >> 16) & 1u);
    return u >> 16;
}
__device__ __forceinline__ float bf16_f32(uint32_t h) {
    return __uint_as_float(h << 16);
}

__device__ __forceinline__ float tanh_fast(float x) {
    float e = __builtin_amdgcn_exp2f(x * 2.8853900817779268f);
    return fmaf(-2.0f, __builtin_amdgcn_rcpf(e + 1.0f), 1.0f);
}

__device__ __forceinline__ int selu4(uint4 v, int T) {
    int x = (T & 1) ? (int)v.y : (int)v.x;
    int y = (T & 1) ? (int)v.w : (int)v.z;
    return (T & 2) ? y : x;
}

// ---- prep: W1 (20x64) -> K-PACKED MFMA A-frags (r10-verified) ----
// A1 = [ah_0..19 | ah_0..11]          (slots 0..19, 20..31)
// A2 = [ah_12..19 | al_0..19 | 0000]  (slots 0..7, 8..27, 28..31 ZERO)
// The A2 zero tail makes B2's last 2 dwords don't-care -> dedup B rows.
__global__ __launch_bounds__(256) void prep_kernel(
    const float* __restrict__ W1_0, const float* __restrict__ W1_1,
    const float* __restrict__ W1_2, uint32_t* __restrict__ wf) {
    int m = blockIdx.x;
    const float* W1 = (m == 0) ? W1_0 : (m == 1) ? W1_1 : W1_2;
    int tid = threadIdx.x;
    int Ht = tid >> 6, lane = tid & 63;
    int n = (lane & 15) + 16 * Ht;
    int kb = (lane >> 4) * 8;
    uint32_t d1[4], d2[4];
#pragma unroll
    for (int q = 0; q < 4; ++q) {
        int k0 = kb + 2 * q, k1 = k0 + 1;
        int ka = (k0 < 20) ? k0 : k0 - 20;
        int kbb = (k1 < 20) ? k1 : k1 - 20;
        uint32_t h0 = bf16_rne(W1[ka * 64 + n]);
        uint32_t h1 = bf16_rne(W1[kbb * 64 + n]);
        d1[q] = h0 | (h1 << 16);
        uint32_t v0, v1;
        {
            int k = k0;
            if (k < 8) {
                v0 = bf16_rne(W1[(k + 12) * 64 + n]);
            } else if (k < 28) {
                float w = W1[(k - 8) * 64 + n];
                uint32_t h = bf16_rne(w);
                v0 = bf16_rne(w - bf16_f32(h));
            } else v0 = 0u;
        }
        {
            int k = k1;
            if (k < 8) {
                v1 = bf16_rne(W1[(k + 12) * 64 + n]);
            } else if (k < 28) {
                float w = W1[(k - 8) * 64 + n];
                uint32_t h = bf16_rne(w);
                v1 = bf16_rne(w - bf16_f32(h));
            } else v1 = 0u;
        }
        d2[q] = v0 | (v1 << 16);
    }
    size_t idx = ((size_t)(m * 4 + Ht) * 64 + lane) * 4;
    *(uint4*)(wf + idx)        = make_uint4(d1[0], d1[1], d1[2], d1[3]);
    *(uint4*)(wf + 3072 + idx) = make_uint4(d2[0], d2[1], d2[2], d2[3]);
}

// Per-cell prologue+classify+pack; numerics identical to verified r10/r11 path.
struct Cell {
    uint32_t pkh[10], pkl[10];
    float hl0, hl1, hl2;
    int wl;
    bool cont, flip;
};

__device__ __forceinline__ void do_cell(
    const float* __restrict__ P, const float* __restrict__ U,
    const float* __restrict__ F, const float* __restrict__ cmax,
    const float* __restrict__ cmin, int cg, bool valid, Cell& o) {
    const float2* P2 = (const float2*)P + (size_t)cg * 3;
    const float2* U2 = (const float2*)U + (size_t)cg * 3;
    const float2* F2 = (const float2*)F + (size_t)cg * 3;
    float2 Pa = P2[0], Pb = P2[1], Pc = P2[2];
    float2 Ua = U2[0], Ub = U2[1], Uc = U2[2];
    float2 Fa = F2[0], Fb = F2[1], Fc = F2[2];
    float cm = cmax[cg];
    float cn = cmin[cg];

    bool flip = Pb.y > Pb.x;
    float fe[20];
    fe[0]  = flip ?  Pa.y :  Pa.x;
    fe[1]  = flip ?  Pa.x :  Pa.y;
    fe[2]  = flip ?  Pb.y :  Pb.x;
    fe[3]  = flip ?  Pb.x :  Pb.y;
    fe[4]  = flip ? -Pc.y :  Pc.x;
    fe[5]  = flip ? -Pc.x :  Pc.y;
    fe[6]  = flip ?  Ua.y :  Ua.x;
    fe[7]  = flip ?  Ua.x :  Ua.y;
    fe[8]  = flip ?  Ub.y :  Ub.x;
    fe[9]  = flip ?  Ub.x :  Ub.y;
    fe[10] = flip ? -Uc.y :  Uc.x;
    fe[11] = flip ? -Uc.x :  Uc.y;
    fe[12] = flip ? -Fa.y :  Fa.x;
    fe[13] = flip ? -Fa.x :  Fa.y;
    fe[14] = flip ? -Fb.y :  Fb.x;
    fe[15] = flip ? -Fb.x :  Fb.y;
    fe[16] = flip ?  Fc.y :  Fc.x;
    fe[17] = flip ?  Fc.x :  Fc.y;
    fe[18] = cm;
    fe[19] = cn;

    double dd0 = fabs((double)fe[1] - (double)fe[0]);
    double dd1 = fabs((double)fe[3] - (double)fe[2]);
    double dd2 = fabs((double)fe[5] - (double)fe[4]);
    bool cont = fmax(fmax(dd0, dd1), dd2) < 0.005;

    float inv = __builtin_amdgcn_rcpf(cm - cn);
    float cmn = cm * cn;
    o.hl0 = (cm * fe[12] - cn * fe[13] + cmn * (fe[7]  - fe[6]))  * inv;
    o.hl1 = (cm * fe[14] - cn * fe[15] + cmn * (fe[9]  - fe[8]))  * inv;
    o.hl2 = (cm * fe[16] - cn * fe[17] + cmn * (fe[11] - fe[10])) * inv;

    float c0f = __builtin_amdgcn_sqrtf(1.6666666f * fe[2] * __builtin_amdgcn_rcpf(fe[0]));
    float c1f = __builtin_amdgcn_sqrtf(1.6666666f * fe[3] * __builtin_amdgcn_rcpf(fe[1]));
    float dvf = fe[5] - fe[4];
    float numf = c0f + c1f - (1.0f / 3.0f) * dvf;
    float pz0 = __builtin_amdgcn_exp2f(-0.2f * __builtin_amdgcn_logf(fe[2]));
    float pz1 = __builtin_amdgcn_exp2f(-0.2f * __builtin_amdgcn_logf(fe[3]));
    float denf = c0f * pz0 + c1f * pz1;
    float tq = fmaxf(numf * __builtin_amdgcn_rcpf(denf), 1e-8f);
    float t2 = tq * tq;
    float psf = t2 * t2 * tq;
    float pminf = fminf(fe[2], fe[3]);
    float pmaxf = fmaxf(fe[2], fe[3]);
    float csum3 = 3.0f * (c0f + c1f);
    float vs = dvf - csum3;
    int label = (vs >= 0.0f) ? 3 : (psf < pminf ? 1 : (psf > pmaxf ? 0 : 2));

    const float eps = 2e-4f;
    bool amb = (fabsf(psf - pminf) <= eps * pminf) ||
               (fabsf(psf - pmaxf) <= eps * pmaxf) ||
               (fabsf(vs) <= eps * (fabsf(dvf) + csum3));
    if (__builtin_expect(amb, 0)) {
        double rho0 = (double)fe[0], rho1 = (double)fe[1];
        double p0   = (double)fe[2], p1   = (double)fe[3];
        double v0   = (double)fe[4], v1   = (double)fe[5];
        const double g = 5.0 / 3.0;
        double c0 = sqrt(g * p0 / rho0);
        double c1 = sqrt(g * p1 / rho1);
        double dv = v1 - v0;
        double z = (g - 1.0) / (2.0 * g);
        double num = c0 + c1 - 0.5 * (g - 1.0) * dv;
        double den = c0 / pow(p0, z) + c1 / pow(p1, z);
        double ps = pow(fmax(num / den, 1e-8), 1.0 / z);
        bool vacd = dv >= 2.0 / (g - 1.0) * (c0 + c1);
        label = vacd ? 3 : (ps < fmin(p0, p1) ? 1 : (ps > fmax(p0, p1) ? 0 : 2));
    }
    o.cont = cont;
    o.flip = flip;
    o.wl = (!valid || cont || label == 3) ? 3 : label;

#pragma unroll
    for (int q = 0; q < 10; ++q) {
        float f0 = fe[2 * q], f1 = fe[2 * q + 1];
        uint32_t h0 = bf16_rne(f0), h1 = bf16_rne(f1);
        uint32_t l0 = bf16_rne(f0 - bf16_f32(h0));
        uint32_t l1 = bf16_rne(f1 - bf16_f32(h1));
        o.pkh[q] = h0 | (h1 << 16);
        o.pkl[q] = l0 | (l1 << 16);
    }
}

// r12 = r11 with DEDUP B-rows: 20 dwords/row (was 32; chunks 5-7 duplicated
// bh only to keep frag2 contiguous). A2's zero slots 28..31 make B2's last 2
// dwords don't-care, so both frags are single per-lane b128 reads from the
// dedup row:  B1 = row dw[4*hi..], B2 = row dw[16..19 | 0..3 | 4..7 | 8..11]
// (hi=3's tail reads bl0,bl1 into the zero-A slots -> product unchanged).
// LDS 75776 -> 51072 B: 2 -> 3 blocks/CU (8 -> 12 waves/CU, +50% chains).
__global__ __launch_bounds__(256, 2) void riemann_fused(
    const float* __restrict__ P, const float* __restrict__ U,
    const float* __restrict__ F, const float* __restrict__ cmax,
    const float* __restrict__ cmin,
    const float* __restrict__ b1_ds, const float* __restrict__ W2_ds, const float* __restrict__ b2_ds,
    const float* __restrict__ b1_dr, const float* __restrict__ W2_dr, const float* __restrict__ b2_dr,
    const float* __restrict__ b1_rs, const float* __restrict__ W2_rs, const float* __restrict__ b2_rs,
    const uint32_t* __restrict__ wf,
    float* __restrict__ out, int N) {
    __shared__ __align__(16) uint32_t sm[512 * 20];      // 40 KiB feats (dedup)
    __shared__ __align__(16) float sw2[3][64][4];        // 3 KiB W2 (padded)
    __shared__ __align__(16) float sb1[3][64];           // 768 B b1
    __shared__ __align__(16) float sflux[512][3];        // 6 KiB flux
    __shared__ __align__(16) uint32_t scnt[32];          // 8 groups x 4 labels

    int tid = threadIdx.x;
    int wv = tid >> 6, lane = tid & 63;
    int hi = lane >> 4, lo16 = lane & 15;
    int base = blockIdx.x * 512;
    int cA = base + tid, cB = base + 256 + tid;
    bool vA = cA < N, vB = cB < N;

    // stage weights early (global loads overlap the prologue)
    if (tid < 192) {
        int mm = tid >> 6, j = tid & 63;
        const float* W2m = (mm == 0) ? W2_ds : (mm == 1) ? W2_dr : W2_rs;
        const float* b1m = (mm == 0) ? b1_ds : (mm == 1) ? b1_dr : b1_rs;
        sw2[mm][j][0] = W2m[j * 3 + 0];
        sw2[mm][j][1] = W2m[j * 3 + 1];
        sw2[mm][j][2] = W2m[j * 3 + 2];
        sw2[mm][j][3] = 0.f;
        sb1[mm][j] = b1m[j];
    }

    Cell oA, oB;
    do_cell(P, U, F, cmax, cmin, vA ? cA : N - 1, vA, oA);
    do_cell(P, U, F, cmax, cmin, vB ? cB : N - 1, vB, oB);

    // ---- block-wide (512) bucket sort via 8 ballot groups ----
    uint64_t aA0 = __ballot(oA.wl == 0);
    uint64_t aA1 = __ballot(oA.wl == 1);
    uint64_t aA2 = __ballot(oA.wl == 2);
    uint64_t aB0 = __ballot(oB.wl == 0);
    uint64_t aB1 = __ballot(oB.wl == 1);
    uint64_t aB2 = __ballot(oB.wl == 2);
    int cA0 = __popcll(aA0), cA1 = __popcll(aA1), cA2 = __popcll(aA2);
    int cB0 = __popcll(aB0), cB1 = __popcll(aB1), cB2 = __popcll(aB2);
    uint64_t lmask = (1ull << lane) - 1ull;
    uint64_t mA = (oA.wl == 0) ? aA0 : (oA.wl == 1) ? aA1 : (oA.wl == 2) ? aA2
                                                         : ~(aA0 | aA1 | aA2);
    uint64_t mB = (oB.wl == 0) ? aB0 : (oB.wl == 1) ? aB1 : (oB.wl == 2) ? aB2
                                                         : ~(aB0 | aB1 | aB2);
    int rankA = (int)__popcll(mA & lmask);
    int rankB = (int)__popcll(mB & lmask);
    if (lane < 8) {
        int l = lane & 3;
        int g = (lane < 4) ? wv : 4 + wv;
        int c = (lane < 4)
            ? ((l == 0) ? cA0 : (l == 1) ? cA1 : (l == 2) ? cA2 : (64 - cA0 - cA1 - cA2))
            : ((l == 0) ? cB0 : (l == 1) ? cB1 : (l == 2) ? cB2 : (64 - cB0 - cB1 - cB2));
        scnt[g * 4 + l] = (uint32_t)c;
    }
    __syncthreads();                               // B1: counts + weights visible
    int T0 = 0, T1 = 0, T2 = 0, prevA = 0, prevB = 0;
#pragma unroll
    for (int g = 0; g < 8; ++g) {
        uint4 q = *(const uint4*)(scnt + 4 * g);
        T0 += (int)q.x; T1 += (int)q.y; T2 += (int)q.z;
        int cag = selu4(q, oA.wl);
        int cbg = selu4(q, oB.wl);
        if (g < wv) prevA += cag;
        if (g < 4 + wv) prevB += cbg;
    }
    int off1 = T0, off2 = T0 + T1, off3 = T0 + T1 + T2;
    int baseA = (oA.wl == 0) ? 0 : (oA.wl == 1) ? off1 : (oA.wl == 2) ? off2 : off3;
    int baseB = (oB.wl == 0) ? 0 : (oB.wl == 1) ? off1 : (oB.wl == 2) ? off2 : off3;
    int slotA = baseA + prevA + rankA;             // 0..511
    int slotB = baseB + prevB + rankB;

    // ---- stage both cells at sorted rows: dedup 20-dword layout ----
    // row = [bh pairs 0..9 (dw0..9) | bl pairs 0..9 (dw10..19)]
    {
        uint32_t* row = sm + (size_t)slotA * 20;
        *(uint4*)(row)      = make_uint4(oA.pkh[0], oA.pkh[1], oA.pkh[2], oA.pkh[3]);
        *(uint4*)(row + 4)  = make_uint4(oA.pkh[4], oA.pkh[5], oA.pkh[6], oA.pkh[7]);
        *(uint4*)(row + 8)  = make_uint4(oA.pkh[8], oA.pkh[9], oA.pkl[0], oA.pkl[1]);
        *(uint4*)(row + 12) = make_uint4(oA.pkl[2], oA.pkl[3], oA.pkl[4], oA.pkl[5]);
        *(uint4*)(row + 16) = make_uint4(oA.pkl[6], oA.pkl[7], oA.pkl[8], oA.pkl[9]);
    }
    {
        uint32_t* row = sm + (size_t)slotB * 20;
        *(uint4*)(row)      = make_uint4(oB.pkh[0], oB.pkh[1], oB.pkh[2], oB.pkh[3]);
        *(uint4*)(row + 4)  = make_uint4(oB.pkh[4], oB.pkh[5], oB.pkh[6], oB.pkh[7]);
        *(uint4*)(row + 8)  = make_uint4(oB.pkh[8], oB.pkh[9], oB.pkl[0], oB.pkl[1]);
        *(uint4*)(row + 12) = make_uint4(oB.pkl[2], oB.pkl[3], oB.pkl[4], oB.pkl[5]);
        *(uint4*)(row + 16) = make_uint4(oB.pkl[6], oB.pkl[7], oB.pkl[8], oB.pkl[9]);
    }
    // zero own wave's flux window (rows 2*tid, 2*tid+1)
    sflux[2 * tid][0] = 0.f; sflux[2 * tid][1] = 0.f; sflux[2 * tid][2] = 0.f;
    sflux[2 * tid + 1][0] = 0.f; sflux[2 * tid + 1][1] = 0.f; sflux[2 * tid + 1][2] = 0.f;
    __syncthreads();                               // B2: feats staged

    // ---- MFMA phase: wave owns 128 sorted rows = 8 tiles ----
    int wbeg = wv * 128, wend = wbeg + 128;
    int c2off = (hi == 0) ? 16 : 4 * (hi - 1);     // B2 per-lane chunk
#pragma unroll 1
    for (int m = 0; m < 3; ++m) {
        int mlo = (m == 0) ? 0 : (m == 1) ? off1 : off2;
        int mhi = (m == 0) ? off1 : (m == 1) ? off2 : off3;
        if (mhi <= wbeg || mlo >= wend) continue;
        bf16x8 af1[4], af2[4];
#pragma unroll
        for (int Ht = 0; Ht < 4; ++Ht) {
            size_t idx = (size_t)((m * 4 + Ht) * 64 + lane);
            af1[Ht] = __builtin_bit_cast(bf16x8, ((const uint4*)wf)[idx]);
            af2[Ht] = __builtin_bit_cast(bf16x8, ((const uint4*)(wf + 3072))[idx]);
        }
#pragma unroll
        for (int t = 0; t < 8; ++t) {
            int tb = wbeg + 16 * t;
            if (mlo < tb + 16 && mhi > tb) {
                const uint32_t* rp = sm + (size_t)(tb + lo16) * 20;
                bf16x8 bf1 = *(const bf16x8*)(rp + 4 * hi);
                bf16x8 bf2 = *(const bf16x8*)(rp + c2off);
                f32x4 acc[4];
#pragma unroll
                for (int Ht = 0; Ht < 4; ++Ht)
                    acc[Ht] = *(const f32x4*)&sb1[m][16 * Ht + 4 * hi];
#pragma unroll
                for (int Ht = 0; Ht < 4; ++Ht)
                    acc[Ht] = __builtin_amdgcn_mfma_f32_16x16x32_bf16(af1[Ht], bf1, acc[Ht], 0, 0, 0);
#pragma unroll
                for (int Ht = 0; Ht < 4; ++Ht)
                    acc[Ht] = __builtin_amdgcn_mfma_f32_16x16x32_bf16(af2[Ht], bf2, acc[Ht], 0, 0, 0);
                float p0 = 0.f, p1 = 0.f, p2 = 0.f;
#pragma unroll
                for (int Ht = 0; Ht < 4; ++Ht) {
#pragma unroll
                    for (int r = 0; r < 4; ++r) {
                        float tv = tanh_fast(acc[Ht][r]);
                        f32x4 w = *(const f32x4*)&sw2[m][16 * Ht + 4 * hi + r][0];
                        p0 = fmaf(tv, w[0], p0);
                        p1 = fmaf(tv, w[1], p1);
                        p2 = fmaf(tv, w[2], p2);
                    }
                }
                int rowp = tb + lo16;
                int lblC = (rowp < off1) ? 0 : (rowp < off2) ? 1 : (rowp < off3) ? 2 : 3;
                float sel = (lblC == m) ? 1.0f : 0.0f;
                p0 *= sel; p1 *= sel; p2 *= sel;
                p0 += __shfl_xor(p0, 16); p0 += __shfl_xor(p0, 32);
                p1 += __shfl_xor(p1, 16); p1 += __shfl_xor(p1, 32);
                p2 += __shfl_xor(p2, 16); p2 += __shfl_xor(p2, 32);
                if (hi == 0) {                     // 16 lanes write 16 rows
                    sflux[rowp][0] += p0;
                    sflux[rowp][1] += p1;
                    sflux[rowp][2] += p2;
                }
            }
        }
    }
    __syncthreads();                               // B3: flux visible

    // ---- epilogue for both cells ----
    {
        float f0, f1, f2;
        if (oA.wl < 3) {
            float bb0 = (oA.wl == 0) ? b2_ds[0] : (oA.wl == 1) ? b2_dr[0] : b2_rs[0];
            float bb1 = (oA.wl == 0) ? b2_ds[1] : (oA.wl == 1) ? b2_dr[1] : b2_rs[1];
            float bb2 = (oA.wl == 0) ? b2_ds[2] : (oA.wl == 1) ? b2_dr[2] : b2_rs[2];
            f0 = sflux[slotA][0] + bb0;
            f1 = sflux[slotA][1] + bb1;
            f2 = sflux[slotA][2] + bb2;
        } else {
            f0 = oA.cont ? oA.hl0 : 0.0f;
            f1 = oA.cont ? oA.hl1 : 0.0f;
            f2 = oA.cont ? oA.hl2 : 0.0f;
        }
        if (oA.flip) { f0 = -f0; f1 = -f1; }
        if (vA) {
            out[(size_t)cA * 3 + 0] = f0;
            out[(size_t)cA * 3 + 1] = f1;
            out[(size_t)cA * 3 + 2] = f2;
        }
    }
    {
        float f0, f1, f2;
        if (oB.wl < 3) {
            float bb0 = (oB.wl == 0) ? b2_ds[0] : (oB.wl == 1) ? b2_dr[0] : b2_rs[0];
            float bb1 = (oB.wl == 0) ? b2_ds[1] : (oB.wl == 1) ? b2_dr[1] : b2_rs[1];
            float bb2 = (oB.wl == 0) ? b2_ds[2] : (oB.wl == 1) ? b2_dr[2] : b2_rs[2];
            f0 = sflux[slotB][0] + bb0;
            f1 = sflux[slotB][1] + bb1;
            f2 = sflux[slotB][2] + bb2;
        } else {
            f0 = oB.cont ? oB.hl0 : 0.0f;
            f1 = oB.cont ? oB.hl1 : 0.0f;
            f2 = oB.cont ? oB.hl2 : 0.0f;
        }
        if (oB.flip) { f0 = -f0; f1 = -f1; }
        if (vB) {
            out[(size_t)cB * 3 + 0] = f0;
            out[(size_t)cB * 3 + 1] = f1;
            out[(size_t)cB * 3 + 2] = f2;
        }
    }
}

extern "C" void kernel_launch(void* const* d_in, const int* in_sizes, int n_in,
                              void* d_out, int out_size, void* d_ws, size_t ws_size,
                              hipStream_t stream) {
    const float* P     = (const float*)d_in[0];
    const float* U     = (const float*)d_in[1];
    const float* F     = (const float*)d_in[2];
    const float* cmax  = (const float*)d_in[3];
    const float* cmin  = (const float*)d_in[4];
    const float* W1_ds = (const float*)d_in[5];
    const float* b1_ds = (const float*)d_in[6];
    const float* W2_ds = (const float*)d_in[7];
    const float* b2_ds = (const float*)d_in[8];
    const float* W1_dr = (const float*)d_in[9];
    const float* b1_dr = (const float*)d_in[10];
    const float* W2_dr = (const float*)d_in[11];
    const float* b2_dr = (const float*)d_in[12];
    const float* W1_rs = (const float*)d_in[13];
    const float* b1_rs = (const float*)d_in[14];
    const float* W2_rs = (const float*)d_in[15];
    const float* b2_rs = (const float*)d_in[16];

    int N = in_sizes[3];
    float* out = (float*)d_out;
    uint32_t* wf = (uint32_t*)d_ws;   // 24 KB: A1 frags 12 KB + A2 frags 12 KB

    hipLaunchKernelGGL(prep_kernel, dim3(3), dim3(256), 0, stream,
                       W1_ds, W1_dr, W1_rs, wf);

    dim3 block(256);
    dim3 grid((N + 511) / 512);
    hipLaunchKernelGGL(riemann_fused, grid, block, 0, stream,
                       P, U, F, cmax, cmin,
                       b1_ds, W2_ds, b2_ds,
                       b1_dr, W2_dr, b2_dr,
                       b1_rs, W2_rs, b2_rs,
                       wf, out, N);
}